// Round 9
// baseline (720.994 us; speedup 1.0000x reference)
//
#include <hip/hip_runtime.h>
#include <cstdint>
#include <cstddef>

constexpr int BB  = 32;
constexpr int TT  = 384;
constexpr int MM  = 1536;
constexpr int W32 = MM / 32;      // 48 bit-windows
constexpr int RPT = 6;            // rows per lane
constexpr float NEGV = -1.0e7f;

// workspace: bits[BB][W32][TT] + A[BB][512]  (~2.4 MB, R1-proven to fit)
constexpr size_t WS_BITS_SZ = (size_t)BB * W32 * TT * 4;
constexpr size_t WS_A_OFF   = WS_BITS_SZ;

// ---------------- tiled transpose: in [b][t][j] -> outT [b][j][t] (R3-proven) ----------------
__global__ __launch_bounds__(256) void mas_transpose(
    const float* __restrict__ in, float* __restrict__ outT)
{
  __shared__ float tile[32][33];
  const int b  = blockIdx.z;
  const int t0 = blockIdx.y * 32, j0 = blockIdx.x * 32;
  const int tx = threadIdx.x, ty = threadIdx.y;
  const float* ip = in  + (size_t)b * TT * MM;
  float*       op = outT + (size_t)b * TT * MM;
#pragma unroll
  for (int i = 0; i < 4; ++i)
    tile[ty + 8 * i][tx] = ip[(size_t)(t0 + ty + 8 * i) * MM + j0 + tx];
  __syncthreads();
#pragma unroll
  for (int i = 0; i < 4; ++i)
    op[(size_t)(j0 + ty + 8 * i) * TT + t0 + tx] = tile[tx][ty + 8 * i];
}

// ---------------- fused DP + backtrack: 1 wave per sample, coalesced input ----------------
// Reads transposed Tq[j][t] (lives in d_out; dense fill overwrites it after).
// Column j = Tq[j*TT + 6k .. +5]: 3 coalesced float2 loads per lane off one
// address register. 8-slot register ring, prefetch distance 6 (slot = col&7,
// written at col-6, read at col, next write at col+2: never aliases).
// __launch_bounds__(64,1): full VGPR budget so the ring stays in registers.
__global__ __launch_bounds__(64, 1) void mas_main(
    const float* __restrict__ Tq, const float* __restrict__ mk0,
    uint32_t* __restrict__ bits, int* __restrict__ A)
{
  const int b = blockIdx.x;
  const int k = threadIdx.x;
  const float* mk = mk0 + (size_t)b * TT * MM;
  uint32_t* bitsS = bits + (size_t)b * W32 * TT;  // [window][row]
  int* Ab = A + b * 512;

  // ---- lengths from mask ----
  float ts = 0.f, ms = 0.f;
  for (int t = k; t < TT; t += 64) ts += mk[(size_t)t * MM];
  for (int j = k; j < MM; j += 64) ms += mk[j];
#pragma unroll
  for (int off = 32; off >= 1; off >>= 1) {
    ts += __shfl_xor(ts, off);
    ms += __shfl_xor(ms, off);
  }
  const int t_len = (int)ts;
  const int m_len = (int)ms;
  for (int t = k; t <= TT; t += 64) Ab[t] = (t >= t_len) ? m_len : 0;

  // ---- forward DP ----
  const int r0 = RPT * k;
  const float* Tp = Tq + (size_t)b * TT * MM;
  float    qp[RPT];
  uint32_t bacc[RPT];
  float2   rg[8][3];                // 8-slot ring, prefetch distance 6
#pragma unroll
  for (int i = 0; i < RPT; ++i) { qp[i] = NEGV; bacc[i] = 0u; }
#pragma unroll
  for (int u = 0; u < 6; ++u) {     // prologue: cols 0..5 -> slots 0..5
    const float* p = Tp + (size_t)u * TT + r0;
    rg[u][0] = *(const float2*)p;
    rg[u][1] = *(const float2*)(p + 2);
    rg[u][2] = *(const float2*)(p + 4);
  }
  for (int w = 0; w < W32; ++w) {
#pragma unroll
    for (int u = 0; u < 32; ++u) {
      const int j = w * 32 + u;
      {  // prefetch col j+6 into slot (u+6)&7 == (j+6)&7
        int jp = j + 6; if (jp > MM - 1) jp = MM - 1;
        const float* p = Tp + (size_t)jp * TT + r0;
        const int s = (u + 6) & 7;
        rg[s][0] = *(const float2*)p;
        rg[s][1] = *(const float2*)(p + 2);
        rg[s][2] = *(const float2*)(p + 4);
      }
      const int cs = u & 7;
      const float x0 = rg[cs][0].x, x1 = rg[cs][0].y;
      const float x2 = rg[cs][1].x, x3 = rg[cs][1].y;
      const float x4 = rg[cs][2].x, x5 = rg[cs][2].y;
      const float sh = __shfl_up(qp[RPT - 1], 1);   // lane k-1 row 6k+5, prev col
      const float qlast = (k == 0) ? ((j == 0) ? 0.0f : NEGV) : sh;
      const uint32_t mbit = 1u << u;
#pragma unroll
      for (int i = RPT - 1; i >= 0; --i) {          // descending: qp[i-1] = prev col
        const float stay = qp[i];
        const float adv  = (i == 0) ? qlast : qp[i - 1];
        const float x = (i == 0) ? x0 : (i == 1) ? x1 : (i == 2) ? x2
                      : (i == 3) ? x3 : (i == 4) ? x4 : x5;
        qp[i] = x + fmaxf(stay, adv);
        if (stay < adv) bacc[i] |= mbit;
      }
    }
#pragma unroll
    for (int i = 0; i < RPT; ++i) { bitsS[w * TT + r0 + i] = bacc[i]; bacc[i] = 0u; }
  }

  asm volatile("s_waitcnt vmcnt(0)" ::: "memory");   // own stores -> own loads

  // ---- backtrack (R3/R6-proven): lane L caches row (t_top - L)'s word ----
  int t = t_len - 1;
  int jj = m_len - 1;
  if (t <= 0 || jj < 1) return;
  int t_top = t;
  int w_cur = jj >> 5;
  uint32_t word;
  { const int row = t_top - k; word = (row >= 0) ? bitsS[w_cur * TT + row] : 0u; }

  for (int guard = 0; guard < 4096; ++guard) {
    const uint32_t cur = __shfl(word, t_top - t);
    const int bpos = jj & 31;
    uint32_t m = cur & ((bpos == 31) ? 0xffffffffu : ((2u << bpos) - 1u));
    if (w_cur == 0) m &= ~1u;
    if (m == 0u) {
      if (w_cur == 0) break;
      --w_cur; jj = (w_cur << 5) | 31;
      t_top = t;
      const int row = t_top - k;
      word = (row >= 0) ? bitsS[w_cur * TT + row] : 0u;
      continue;
    }
    const int p = 31 - __builtin_clz(m);
    jj = (w_cur << 5) | p;
    if (k == 0) Ab[t] = jj;
    --t; --jj;
    if (t <= 0 || jj < 1) break;
    const int wn = jj >> 5;
    if (wn != w_cur || (t_top - t) > 63) {
      w_cur = wn; t_top = t;
      const int row = t_top - k;
      word = (row >= 0) ? bitsS[w_cur * TT + row] : 0u;
    }
  }
}

// ---------------- dense fill (R6-proven, ~20 us): overwrites Tq remnants ----------------
__global__ __launch_bounds__(256) void mas_fill(
    const int* __restrict__ A, float* __restrict__ out)
{
  const int idx = blockIdx.x * 256 + threadIdx.x;   // over B*T*(M/4)
  const int nj4 = MM / 4;
  const int j4 = (idx % nj4) * 4;
  const int t  = (idx / nj4) % TT;
  const int b  = idx / (nj4 * TT);
  const int a  = A[b * 512 + t];
  const int e  = A[b * 512 + t + 1];
  float4 v;
  v.x = (j4 + 0 >= a && j4 + 0 < e) ? 1.0f : 0.0f;
  v.y = (j4 + 1 >= a && j4 + 1 < e) ? 1.0f : 0.0f;
  v.z = (j4 + 2 >= a && j4 + 2 < e) ? 1.0f : 0.0f;
  v.w = (j4 + 3 >= a && j4 + 3 < e) ? 1.0f : 0.0f;
  reinterpret_cast<float4*>(out)[idx] = v;
}

extern "C" void kernel_launch(void* const* d_in, const int* in_sizes, int n_in,
                              void* d_out, int out_size, void* d_ws, size_t ws_size,
                              hipStream_t stream) {
  const float* log_p = (const float*)d_in[0];
  const float* maskp = (const float*)d_in[1];
  float* out = (float*)d_out;
  uint32_t* bits = (uint32_t*)d_ws;
  int* A = (int*)((char*)d_ws + WS_A_OFF);
  float* Tq = out;   // d_out holds the transpose until mas_fill overwrites it

  mas_transpose<<<dim3(MM / 32, TT / 32, BB), dim3(32, 8), 0, stream>>>(log_p, Tq);
  mas_main<<<BB, 64, 0, stream>>>(Tq, maskp, bits, A);
  mas_fill<<<(BB * TT * (MM / 4)) / 256, 256, 0, stream>>>(A, out);
}

// Round 10
// 507.692 us; speedup vs baseline: 1.4201x; 1.4201x over previous
//
#include <hip/hip_runtime.h>
#include <cstdint>
#include <cstddef>

constexpr int BB  = 32;
constexpr int TT  = 384;
constexpr int MM  = 1536;
constexpr int W32 = MM / 32;      // 48 bit-windows
constexpr int RPT = 6;            // rows per lane
constexpr float NEGV = -1.0e7f;

// workspace: bits[BB][W32][TT] + A[BB][512]
constexpr size_t WS_BITS_SZ = (size_t)BB * W32 * TT * 4;
constexpr size_t WS_A_OFF   = WS_BITS_SZ;

typedef const __attribute__((address_space(1))) uint32_t glb_u32;
typedef __attribute__((address_space(3))) uint32_t lds_u32;

// ---------------- tiled transpose: in [b][t][j] -> outT [b][j][t] (R3-proven) ----------------
__global__ __launch_bounds__(256) void mas_transpose(
    const float* __restrict__ in, float* __restrict__ outT)
{
  __shared__ float tile[32][33];
  const int b  = blockIdx.z;
  const int t0 = blockIdx.y * 32, j0 = blockIdx.x * 32;
  const int tx = threadIdx.x, ty = threadIdx.y;
  const float* ip = in  + (size_t)b * TT * MM;
  float*       op = outT + (size_t)b * TT * MM;
#pragma unroll
  for (int i = 0; i < 4; ++i)
    tile[ty + 8 * i][tx] = ip[(size_t)(t0 + ty + 8 * i) * MM + j0 + tx];
  __syncthreads();
#pragma unroll
  for (int i = 0; i < 4; ++i)
    op[(size_t)(j0 + ty + 8 * i) * TT + t0 + tx] = tile[tx][ty + 8 * i];
}

// ---------------- fused DP + backtrack: 1 wave/sample, async LDS staging ----------------
// Columns stream global->LDS via global_load_lds (no dest registers => the
// compiler cannot sink the prefetch, unlike R3/R9's register rings).
// Ring: 16 slots x 2 cols x 384 floats = 48 KB. Consume granularity: group =
// 8 cols (4 slots); prefetch 3 groups (24 cols) ahead; one s_waitcnt vmcnt(36)
// per group (36 = the 3 newer in-flight groups' loads; bit stores interleaved
// only make the wait stronger). Last 3 groups: vmcnt(0).
__global__ __launch_bounds__(64, 1) void mas_main(
    const float* __restrict__ Tq, const float* __restrict__ mk0,
    uint32_t* __restrict__ bits, int* __restrict__ A)
{
  __shared__ float xs[16 * 768];                  // 49,152 B
  const int b = blockIdx.x;
  const int k = threadIdx.x;
  const float* mk = mk0 + (size_t)b * TT * MM;
  uint32_t* bitsS = bits + (size_t)b * W32 * TT;  // [window][row]
  int* Ab = A + b * 512;

  // ---- lengths from mask (before any prefetch: keeps compiler waits cheap) ----
  float ts = 0.f, ms = 0.f;
  for (int t = k; t < TT; t += 64) ts += mk[(size_t)t * MM];
  for (int j = k; j < MM; j += 64) ms += mk[j];
#pragma unroll
  for (int off = 32; off >= 1; off >>= 1) {
    ts += __shfl_xor(ts, off);
    ms += __shfl_xor(ms, off);
  }
  const int t_len = (int)ts;
  const int m_len = (int)ms;
  for (int t = k; t <= TT; t += 64) Ab[t] = (t >= t_len) ? m_len : 0;

  const float* Tp = Tq + (size_t)b * TT * MM;     // [j][t]
  const int r0 = RPT * k;
  float    qp[RPT];
  uint32_t bacc[RPT];
#pragma unroll
  for (int i = 0; i < RPT; ++i) { qp[i] = NEGV; bacc[i] = 0u; }

  // ---- prologue: prefetch groups 0..2 (slots 0..11; slot = 2 cols = 3 insts) ----
#pragma unroll
  for (int s = 0; s < 12; ++s)
#pragma unroll
    for (int h = 0; h < 3; ++h)
      __builtin_amdgcn_global_load_lds(
          (glb_u32*)(Tp + (size_t)s * 768 + h * 256 + 4 * k),
          (lds_u32*)&xs[s * 768 + h * 256], 16, 0, 0);

  // ---- main loop: 48 windows x 4 groups x 8 cols ----
  for (int w = 0; w < W32; ++w) {
#pragma unroll
    for (int q = 0; q < 4; ++q) {
      const int G  = 4 * w + q;
      const int Gp = G + 3;
      if (Gp < 192) {                             // prefetch group Gp
        const int phase = ((q + 3) & 3) * 4;      // slot base (compile-time)
#pragma unroll
        for (int s = 0; s < 4; ++s)
#pragma unroll
          for (int h = 0; h < 3; ++h)
            __builtin_amdgcn_global_load_lds(
                (glb_u32*)(Tp + (size_t)(8 * Gp + 2 * s) * TT + h * 256 + 4 * k),
                (lds_u32*)&xs[(phase + s) * 768 + h * 256], 16, 0, 0);
      }
      if (w < W32 - 1 || q == 0)
        asm volatile("s_waitcnt vmcnt(36)" ::: "memory");
      else
        asm volatile("s_waitcnt vmcnt(0)" ::: "memory");

      // consume 8 columns of group G from slots q*4 .. q*4+3
#pragma unroll
      for (int cc = 0; cc < 8; ++cc) {
        const int sid = q * 4 + (cc >> 1);
        const float* cp = &xs[sid * 768 + (cc & 1) * 384 + r0];
        const float2 a0 = *(const float2*)cp;
        const float2 a1 = *(const float2*)(cp + 2);
        const float2 a2 = *(const float2*)(cp + 4);
        const int jbit = 8 * q + cc;              // j & 31 (compile-time)
        const int j = 32 * w + jbit;
        const float sh = __shfl_up(qp[RPT - 1], 1);   // lane k-1 row 6k+5, prev col
        const float qlast = (k == 0) ? ((j == 0) ? 0.0f : NEGV) : sh;
        const uint32_t mbit = 1u << jbit;
        const float x0 = a0.x, x1 = a0.y, x2 = a1.x, x3 = a1.y, x4 = a2.x, x5 = a2.y;
#pragma unroll
        for (int i = RPT - 1; i >= 0; --i) {      // descending: qp[i-1] = prev col
          const float stay = qp[i];
          const float adv  = (i == 0) ? qlast : qp[i - 1];
          const float x = (i == 0) ? x0 : (i == 1) ? x1 : (i == 2) ? x2
                        : (i == 3) ? x3 : (i == 4) ? x4 : x5;
          qp[i] = x + fmaxf(stay, adv);
          if (stay < adv) bacc[i] |= mbit;
        }
      }
    }
#pragma unroll
    for (int i = 0; i < RPT; ++i) { bitsS[w * TT + r0 + i] = bacc[i]; bacc[i] = 0u; }
  }

  asm volatile("s_waitcnt vmcnt(0)" ::: "memory");   // own bit-stores -> own loads

  // ---- backtrack (R3/R6-proven): lane L caches row (t_top - L)'s word ----
  int t = t_len - 1;
  int jj = m_len - 1;
  if (t <= 0 || jj < 1) return;
  int t_top = t;
  int w_cur = jj >> 5;
  uint32_t word;
  { const int row = t_top - k; word = (row >= 0) ? bitsS[w_cur * TT + row] : 0u; }

  for (int guard = 0; guard < 4096; ++guard) {
    const uint32_t cur = __shfl(word, t_top - t);
    const int bpos = jj & 31;
    uint32_t m = cur & ((bpos == 31) ? 0xffffffffu : ((2u << bpos) - 1u));
    if (w_cur == 0) m &= ~1u;
    if (m == 0u) {
      if (w_cur == 0) break;
      --w_cur; jj = (w_cur << 5) | 31;
      t_top = t;
      const int row = t_top - k;
      word = (row >= 0) ? bitsS[w_cur * TT + row] : 0u;
      continue;
    }
    const int p = 31 - __builtin_clz(m);
    jj = (w_cur << 5) | p;
    if (k == 0) Ab[t] = jj;
    --t; --jj;
    if (t <= 0 || jj < 1) break;
    const int wn = jj >> 5;
    if (wn != w_cur || (t_top - t) > 63) {
      w_cur = wn; t_top = t;
      const int row = t_top - k;
      word = (row >= 0) ? bitsS[w_cur * TT + row] : 0u;
    }
  }
}

// ---------------- dense fill (proven): overwrites Tq remnants in d_out ----------------
__global__ __launch_bounds__(256) void mas_fill(
    const int* __restrict__ A, float* __restrict__ out)
{
  const int idx = blockIdx.x * 256 + threadIdx.x;   // over B*T*(M/4)
  const int nj4 = MM / 4;
  const int j4 = (idx % nj4) * 4;
  const int t  = (idx / nj4) % TT;
  const int b  = idx / (nj4 * TT);
  const int a  = A[b * 512 + t];
  const int e  = A[b * 512 + t + 1];
  float4 v;
  v.x = (j4 + 0 >= a && j4 + 0 < e) ? 1.0f : 0.0f;
  v.y = (j4 + 1 >= a && j4 + 1 < e) ? 1.0f : 0.0f;
  v.z = (j4 + 2 >= a && j4 + 2 < e) ? 1.0f : 0.0f;
  v.w = (j4 + 3 >= a && j4 + 3 < e) ? 1.0f : 0.0f;
  reinterpret_cast<float4*>(out)[idx] = v;
}

extern "C" void kernel_launch(void* const* d_in, const int* in_sizes, int n_in,
                              void* d_out, int out_size, void* d_ws, size_t ws_size,
                              hipStream_t stream) {
  const float* log_p = (const float*)d_in[0];
  const float* maskp = (const float*)d_in[1];
  float* out = (float*)d_out;
  uint32_t* bits = (uint32_t*)d_ws;
  int* A = (int*)((char*)d_ws + WS_A_OFF);
  float* Tq = out;   // d_out holds the transpose until mas_fill overwrites it

  mas_transpose<<<dim3(MM / 32, TT / 32, BB), dim3(32, 8), 0, stream>>>(log_p, Tq);
  mas_main<<<BB, 64, 0, stream>>>(Tq, maskp, bits, A);
  mas_fill<<<(BB * TT * (MM / 4)) / 256, 256, 0, stream>>>(A, out);
}